// Round 12
// baseline (68.857 us; speedup 1.0000x reference)
//
#include <hip/hip_runtime.h>
#include <hip/hip_bf16.h>

#define VOCAB 50257
#define NTAGS 50
#define EMB   128
#define NTOK  262144
#define KD    640     // (2*CTX+1) * EMB
#define WPAD  64      // (fallback) tags padded to 4 MFMA tiles

#define TAGP  64      // per-position padded tag slots (slice = 128 B, line-aligned)
#define NZ    320     // 5 positions * TAGP
#define ZROWS 50304   // 393*128 rows (rows >= VOCAB are zero sentinels)

#define TOK   24      // tokens per tag_k block (LDS ~18 KB -> 8 blocks/CU)
#define RWS   28      // staged rows (24 + 4 halo)
#define CHR   40      // 16B chunks per ZT row (640 B)
#define NCHUNK (RWS*CHR)          // 1120
#define NITER  ((NCHUNK+63)/64)   // 18

typedef __attribute__((ext_vector_type(4))) float f32x4;
typedef __attribute__((ext_vector_type(8))) short bf16x8;

__device__ __forceinline__ ushort f2bf(float f) {
    union { float f; unsigned u; } v; v.f = f;
    unsigned u = v.u;
    return (ushort)((u + 0x7fffu + ((u >> 16) & 1u)) >> 16);  // RNE
}

__device__ __forceinline__ void gload_lds16(const void* g, void* l) {
    __builtin_amdgcn_global_load_lds(
        (const __attribute__((address_space(1))) unsigned*)g,
        (__attribute__((address_space(3))) unsigned*)l, 16, 0, 0);
}

// ============================ primary path ============================

// ZT[v][p*64+tag] = emb[v] . W[tag][p*128 : p*128+128]   (bf16 out)
// 393 blocks x 4 waves, 128 vocab rows each. W fp32 staged to LDS in-kernel.
// MFMA operands SWAPPED (A=W tags, B=emb rows) so lane owns one vocab row and
// 4-consecutive-tag runs -> packed ushort4 stores (L2 merges to full lines).
__global__ __launch_bounds__(256)
void zt_k(const float* __restrict__ emb, const float* __restrict__ W,
          ushort* __restrict__ ZT) {
    __shared__ __align__(16) char wlds[NZ * EMB * 2];   // 80 KB, chunk-swizzled

    const int tid  = threadIdx.x;
    const int lane = tid & 63;
    const int wave = tid >> 6;
    const int c = lane & 15, q = lane >> 4;
    const int vb = blockIdx.x * 128;

    // ---- stage W (fp32) -> bf16 LDS: 5120 chunks of 16 B.
    //      phys chunk j of row n holds logical chunk j^(n&7). ----
    #pragma unroll
    for (int it = 0; it < 20; ++it) {
        int g = it * 256 + tid;           // flat chunk = n*16 + j
        int n = g >> 4, j = g & 15;
        int tg = n & 63, p = n >> 6;
        bf16x8 val = (bf16x8){0,0,0,0,0,0,0,0};
        if (tg < NTAGS) {
            const float* wp = W + tg * KD + p * EMB + j * 8;
            f32x4 lo = *(const f32x4*)wp;
            f32x4 hi = *(const f32x4*)(wp + 4);
            val[0]=(short)f2bf(lo[0]); val[1]=(short)f2bf(lo[1]);
            val[2]=(short)f2bf(lo[2]); val[3]=(short)f2bf(lo[3]);
            val[4]=(short)f2bf(hi[0]); val[5]=(short)f2bf(hi[1]);
            val[6]=(short)f2bf(hi[2]); val[7]=(short)f2bf(hi[3]);
        }
        *(bf16x8*)(wlds + n * 256 + ((j ^ (n & 7)) << 4)) = val;
    }

    // ---- E: this wave's 32 vocab rows (2 n-tiles), fp32 -> bf16 in regs ----
    bf16x8 E[2][4];
    #pragma unroll
    for (int nv = 0; nv < 2; ++nv) {
        int row = vb + wave * 32 + nv * 16 + c;
        bool ok = row < VOCAB;
        const float* rp = emb + (size_t)(ok ? row : 0) * EMB;
        #pragma unroll
        for (int kk = 0; kk < 4; ++kk) {
            f32x4 lo = {0,0,0,0}, hi = {0,0,0,0};
            if (ok) {
                lo = *(const f32x4*)(rp + kk * 32 + q * 8);
                hi = *(const f32x4*)(rp + kk * 32 + q * 8 + 4);
            }
            bf16x8 a;
            a[0]=(short)f2bf(lo[0]); a[1]=(short)f2bf(lo[1]);
            a[2]=(short)f2bf(lo[2]); a[3]=(short)f2bf(lo[3]);
            a[4]=(short)f2bf(hi[0]); a[5]=(short)f2bf(hi[1]);
            a[6]=(short)f2bf(hi[2]); a[7]=(short)f2bf(hi[3]);
            E[nv][kk] = a;
        }
    }
    __syncthreads();

    #pragma unroll
    for (int ng = 0; ng < 5; ++ng) {        // ng == position p
        bf16x8 Wf[4][4];
        #pragma unroll
        for (int mtag = 0; mtag < 4; ++mtag) {
            #pragma unroll
            for (int kk = 0; kk < 4; ++kk) {
                int r  = ng * 64 + mtag * 16 + c;         // Wt row
                int ph = (kk * 4 + q) ^ (c & 7);          // phys chunk (r&7 == c&7)
                Wf[mtag][kk] = *(const bf16x8*)(wlds + r * 256 + ph * 16);
            }
        }
        f32x4 acc[4][2];
        #pragma unroll
        for (int mtag = 0; mtag < 4; ++mtag)
            #pragma unroll
            for (int nv = 0; nv < 2; ++nv)
                acc[mtag][nv] = (f32x4){0.f,0.f,0.f,0.f};
        #pragma unroll
        for (int kk = 0; kk < 4; ++kk)
            #pragma unroll
            for (int mtag = 0; mtag < 4; ++mtag)
                #pragma unroll
                for (int nv = 0; nv < 2; ++nv)
                    acc[mtag][nv] = __builtin_amdgcn_mfma_f32_16x16x32_bf16(
                        Wf[mtag][kk], E[nv][kk], acc[mtag][nv], 0, 0, 0);
        // D[tag=(q*4+j)][v=c]: lane owns vocab row (.. + nv*16 + c),
        // tags mtag*16 + q*4 + j  -> one ushort4 (8B) store per (mtag,nv).
        #pragma unroll
        for (int nv = 0; nv < 2; ++nv) {
            const size_t row = (size_t)(vb + wave * 32 + nv * 16 + c);
            #pragma unroll
            for (int mtag = 0; mtag < 4; ++mtag) {
                ushort4 o = { f2bf(acc[mtag][nv][0]), f2bf(acc[mtag][nv][1]),
                              f2bf(acc[mtag][nv][2]), f2bf(acc[mtag][nv][3]) };
                *(ushort4*)(ZT + row * NZ + ng * 64 + mtag * 16 + q * 4) = o;
            }
        }
    }
}

// per 24-token block: ids->LDS prefetch, batched reg reads, then fully
// independent coalesced gload_lds staging of 28 ZT rows; window-sum,
// softmax, LDS-transpose full-line stores.  ~18 KB LDS -> 8 blocks/CU.
__global__ __launch_bounds__(64, 1)
void tag_k(const int* __restrict__ tokens, const ushort* __restrict__ ZT,
           const float* __restrict__ bias, float* __restrict__ out) {
    __shared__ __align__(16) char smem[RWS * 640 + 128];   // rows + ids
    int* ids = (int*)(smem + RWS * 640);

    const int l  = threadIdx.x;
    const int bb = blockIdx.x * TOK;

    // ---- token ids for the 28 rows (row r <-> token bb-2+r) ----
    {
        int t = bb - 2 + l;
        if (l < RWS) ids[l] = ((unsigned)t < NTOK) ? tokens[t] : VOCAB; // zero row
    }
    __syncthreads();

    // ---- batched id reads into regs (mostly-broadcast LDS reads) ----
    int tk[NITER];
    #pragma unroll
    for (int w = 0; w < NITER; ++w) {
        int g = w * 64 + l;
        int r = (g < NCHUNK) ? (g / CHR) : 0;
        tk[w] = ids[r];
    }

    // ---- coalesced stage: flat chunk g = r*40 + p*8 + i  ->  LDS byte g*16.
    //      all DMA issues independent (ids already in regs); source chunk
    //      pre-swizzled (i ^ (r&7)) so LDS dest stays linear. ----
    #pragma unroll
    for (int w = 0; w < NITER; ++w) {
        int g = w * 64 + l;
        if (g < NCHUNK) {
            int r  = g / CHR;
            int ch = g - r * CHR;
            int i  = ch & 7, p = ch >> 3;
            const char* src = (const char*)ZT + (size_t)tk[w] * 640
                              + p * 128 + ((i ^ (r & 7)) << 4);
            gload_lds16(src, smem + w * 1024);
        }
    }
    __syncthreads();

    // ---- accumulate bias + 5 window slices: slice p of token bb+l lives in
    //      LDS row l+p (token bb+l+p-2). ----
    float acc[56];
    #pragma unroll
    for (int g = 0; g < 12; ++g) {
        float4 b4 = *(const float4*)(bias + g * 4);
        acc[g*4+0] = b4.x; acc[g*4+1] = b4.y; acc[g*4+2] = b4.z; acc[g*4+3] = b4.w;
    }
    acc[48] = bias[48]; acc[49] = bias[49];
    #pragma unroll
    for (int j = 50; j < 56; ++j) acc[j] = 0.f;

    {
        const int le = (l < TOK) ? l : (TOK - 1);   // lanes 24..63: dummy rows
        bf16x8 v[5][7];
        #pragma unroll
        for (int p = 0; p < 5; ++p) {
            const int rp = le + p;                  // LDS row for this slice
            const char* rb = smem + rp * 640;
            const int rx = (rp & 7) << 4;
            #pragma unroll
            for (int j = 0; j < 7; ++j)
                v[p][j] = *(const bf16x8*)(rb + p * 128 + ((j << 4) ^ rx));
        }
        #pragma unroll
        for (int p = 0; p < 5; ++p)
            #pragma unroll
            for (int j = 0; j < 7; ++j)
                #pragma unroll
                for (int e = 0; e < 8; ++e) {
                    unsigned u = (unsigned)(ushort)v[p][j][e] << 16;
                    acc[j*8+e] += __uint_as_float(u);
                }
    }

    // ---- log-softmax over tags 0..49 (all local to the lane) ----
    float m = acc[0];
    #pragma unroll
    for (int j = 1; j < NTAGS; ++j) m = fmaxf(m, acc[j]);
    float s = 0.f;
    #pragma unroll
    for (int j = 0; j < NTAGS; ++j) s += __expf(acc[j] - m);
    const float L = m + __logf(s);

    // ---- LDS transpose -> full-line coalesced stores ----
    __syncthreads();
    if (l < TOK) {
        #pragma unroll
        for (int k = 0; k < 25; ++k) {
            float2 st = { acc[2*k] - L, acc[2*k+1] - L };
            *(float2*)(smem + (size_t)l * 200 + k * 8) = st;
        }
    }
    __syncthreads();
    const int nvalid = (NTOK - bb < TOK) ? (NTOK - bb) : TOK;
    const int nbytes = nvalid * 200;
    char* ob = (char*)out + (size_t)bb * 200;
    #pragma unroll
    for (int w = 0; w < 5; ++w) {
        int off = w * 1024 + l * 16;
        if (off < nbytes) {
            f32x4 d = *(const f32x4*)(smem + off);
            *(f32x4*)(ob + off) = d;
        }
    }
}

// ============================ fallback path (R4, needs only ~13 MB ws) ============================
__global__ void fb_conv_k(const float* __restrict__ emb, const float* __restrict__ W,
                          ushort* __restrict__ embb, ushort* __restrict__ wb) {
    const int etotal = (VOCAB + 1) * EMB;
    int idx = (blockIdx.x * blockDim.x + threadIdx.x) * 4;
    if (idx < etotal) {
        float4 v = {0.f, 0.f, 0.f, 0.f};
        if (idx < VOCAB * EMB) v = *(const float4*)(emb + idx);
        ushort4 o = { f2bf(v.x), f2bf(v.y), f2bf(v.z), f2bf(v.w) };
        *(ushort4*)(embb + idx) = o;
    } else {
        int wi = idx - etotal;
        if (wi < WPAD * KD) {
            #pragma unroll
            for (int k = 0; k < 4; ++k) {
                int j = wi + k;
                int tag = j / KD;
                wb[j] = f2bf(tag < NTAGS ? W[j] : 0.f);
            }
        }
    }
}

__global__ __launch_bounds__(64, 2)
void fb_tag_k(const int* __restrict__ tokens, const ushort* __restrict__ embb,
              const ushort* __restrict__ Wb, const float* __restrict__ bias,
              float* __restrict__ out) {
    __shared__ ushort smem[68 * EMB];
    const int lane = threadIdx.x & 63;
    const int c = lane & 15;
    const int q = lane >> 4;
    const int bb = blockIdx.x * 64;
    const int rsub = lane >> 4;

    int tokid[17];
    #pragma unroll
    for (int g = 0; g < 17; ++g) {
        int t = bb - 2 + g * 4 + rsub;
        tokid[g] = (t >= 0 && t < NTOK) ? tokens[t] : VOCAB;
    }
    const ushort* bp[4];
    #pragma unroll
    for (int nt = 0; nt < 4; ++nt)
        bp[nt] = Wb + (nt * 16 + c) * KD + q * 8;
    bf16x8 Bb[4][4];
    #pragma unroll
    for (int s = 0; s < 4; ++s)
        #pragma unroll
        for (int nt = 0; nt < 4; ++nt)
            Bb[s][nt] = *(const bf16x8*)(bp[nt] + (s >> 2) * 128 + (s & 3) * 32);
    float bv[4];
    #pragma unroll
    for (int nt = 0; nt < 4; ++nt) {
        int tag = nt * 16 + c;
        bv[nt] = bias[tag < NTAGS ? tag : NTAGS - 1];
    }
    {
        const int pc = lane & 15;
        #pragma unroll
        for (int g = 0; g < 17; ++g) {
            int i = g * 4 + rsub;
            int sc = pc ^ (i & 7);
            gload_lds16(embb + (size_t)tokid[g] * EMB + sc * 8, (char*)smem + g * 1024);
        }
    }
    __syncthreads();

    f32x4 acc[4][4];
    #pragma unroll
    for (int mt = 0; mt < 4; ++mt)
        #pragma unroll
        for (int nt = 0; nt < 4; ++nt)
            acc[mt][nt] = (f32x4){0.f, 0.f, 0.f, 0.f};
    bf16x8 Ab[2][4];
    #pragma unroll
    for (int s = 0; s < 2; ++s) {
        int p = s >> 2, kk = s & 3;
        int ch = (4 * kk + q) ^ ((c + p) & 7);
        const char* ab = (const char*)smem + (c + p) * 256 + ch * 16;
        #pragma unroll
        for (int mt = 0; mt < 4; ++mt)
            Ab[s][mt] = *(const bf16x8*)(ab + mt * 4096);
    }
    #pragma unroll
    for (int s = 0; s < 20; ++s) {
        __builtin_amdgcn_s_setprio(1);
        #pragma unroll
        for (int mt = 0; mt < 4; ++mt)
            #pragma unroll
            for (int nt = 0; nt < 4; ++nt)
                acc[mt][nt] = __builtin_amdgcn_mfma_f32_16x16x32_bf16(
                    Ab[s & 1][mt], Bb[s & 3][nt], acc[mt][nt], 0, 0, 0);
        __builtin_amdgcn_s_setprio(0);
        if (s + 4 < 20) {
            const int tt = s + 4, p = tt >> 2, kk = tt & 3;
            #pragma unroll
            for (int nt = 0; nt < 4; ++nt)
                Bb[s & 3][nt] = *(const bf16x8*)(bp[nt] + p * 128 + kk * 32);
        }
        if (s + 2 < 20) {
            const int tt = s + 2, p = tt >> 2, kk = tt & 3;
            int ch = (4 * kk + q) ^ ((c + p) & 7);
            const char* ab = (const char*)smem + (c + p) * 256 + ch * 16;
            #pragma unroll
            for (int mt = 0; mt < 4; ++mt)
                Ab[s & 1][mt] = *(const bf16x8*)(ab + mt * 4096);
        }
    }
    #pragma unroll
    for (int mt = 0; mt < 4; ++mt) {
        #pragma unroll
        for (int j = 0; j < 4; ++j) {
            const int row = bb + mt * 16 + q * 4 + j;
            float x[4];
            float m = -1e30f;
            #pragma unroll
            for (int nt = 0; nt < 4; ++nt) {
                float xv = acc[mt][nt][j] + bv[nt];
                x[nt] = xv;
                if (nt * 16 + c < NTAGS) m = fmaxf(m, xv);
            }
            #pragma unroll
            for (int mask = 8; mask >= 1; mask >>= 1)
                m = fmaxf(m, __shfl_xor(m, mask));
            float s = 0.f;
            #pragma unroll
            for (int nt = 0; nt < 4; ++nt)
                if (nt * 16 + c < NTAGS) s += __expf(x[nt] - m);
            #pragma unroll
            for (int mask = 8; mask >= 1; mask >>= 1)
                s += __shfl_xor(s, mask);
            const float L = m + __logf(s);
            #pragma unroll
            for (int nt = 0; nt < 4; ++nt) {
                int tag = nt * 16 + c;
                if (tag < NTAGS) out[row * NTAGS + tag] = x[nt] - L;
            }
        }
    }
}

extern "C" void kernel_launch(void* const* d_in, const int* in_sizes, int n_in,
                              void* d_out, int out_size, void* d_ws, size_t ws_size,
                              hipStream_t stream) {
    const int*   tokens = (const int*)d_in[0];
    const float* emb    = (const float*)d_in[1];
    const float* W      = (const float*)d_in[2];
    const float* b      = (const float*)d_in[3];
    float* out = (float*)d_out;

    const size_t NEED = (size_t)ZROWS * NZ * 2ull;   // ~32.2 MB
    if (ws_size >= NEED) {
        ushort* ZT = (ushort*)d_ws;                  // ZROWS x 320 bf16
        zt_k<<<ZROWS / 128, 256, 0, stream>>>(emb, W, ZT);
        tag_k<<<(NTOK + TOK - 1) / TOK, 64, 0, stream>>>(tokens, ZT, b, out);
    } else {
        ushort* embb = (ushort*)d_ws;
        ushort* Wb   = embb + (size_t)(VOCAB + 1) * EMB;
        const int etotal = (VOCAB + 1) * EMB;
        const int total4 = (etotal + WPAD * KD) / 4;
        fb_conv_k<<<(total4 + 255) / 256, 256, 0, stream>>>(emb, W, embb, Wb);
        fb_tag_k<<<NTOK / 64, 64, 0, stream>>>(tokens, embb, Wb, b, out);
    }
}

// Round 13
// 68.071 us; speedup vs baseline: 1.0115x; 1.0115x over previous
//
#include <hip/hip_runtime.h>
#include <hip/hip_bf16.h>

#define VOCAB 50257
#define NTAGS 50
#define EMB   128
#define NTOK  262144
#define KD    640     // (2*CTX+1) * EMB
#define WPAD  64      // (fallback) tags padded to 4 MFMA tiles

#define TAGP  64      // per-position padded tag slots (slice = 128 B, line-aligned)
#define NZ    320     // 5 positions * TAGP
#define ZROWS 50304   // 393*128 rows (rows >= VOCAB are zero sentinels)

#define TOK   24      // tokens per tag_k block (LDS ~18 KB -> 8 blocks/CU)
#define RWS   28      // staged rows (24 + 4 halo)
#define CHR   40      // 16B chunks per ZT row (640 B)
#define NCHUNK (RWS*CHR)          // 1120
#define NITER  ((NCHUNK+63)/64)   // 18

typedef __attribute__((ext_vector_type(4))) float f32x4;
typedef __attribute__((ext_vector_type(8))) short bf16x8;

__device__ __forceinline__ ushort f2bf(float f) {
    union { float f; unsigned u; } v; v.f = f;
    unsigned u = v.u;
    return (ushort)((u + 0x7fffu + ((u >> 16) & 1u)) >> 16);  // RNE
}

__device__ __forceinline__ void gload_lds16(const void* g, void* l) {
    __builtin_amdgcn_global_load_lds(
        (const __attribute__((address_space(1))) unsigned*)g,
        (__attribute__((address_space(3))) unsigned*)l, 16, 0, 0);
}

// ============================ primary path ============================

// ZT[v][p*64+tag] = emb[v] . W[tag][p*128 : p*128+128]   (bf16 out)
// 393 blocks x 4 waves, 128 vocab rows each. W fp32 staged to LDS in-kernel.
// MFMA operands SWAPPED (A=W tags, B=emb rows) so lane owns one vocab row and
// 4-consecutive-tag runs -> packed ushort4 stores (L2 merges to full lines).
__global__ __launch_bounds__(256)
void zt_k(const float* __restrict__ emb, const float* __restrict__ W,
          ushort* __restrict__ ZT) {
    __shared__ __align__(16) char wlds[NZ * EMB * 2];   // 80 KB, chunk-swizzled

    const int tid  = threadIdx.x;
    const int lane = tid & 63;
    const int wave = tid >> 6;
    const int c = lane & 15, q = lane >> 4;
    const int vb = blockIdx.x * 128;

    // ---- stage W (fp32) -> bf16 LDS: 5120 chunks of 16 B.
    //      phys chunk j of row n holds logical chunk j^(n&7). ----
    #pragma unroll
    for (int it = 0; it < 20; ++it) {
        int g = it * 256 + tid;           // flat chunk = n*16 + j
        int n = g >> 4, j = g & 15;
        int tg = n & 63, p = n >> 6;
        bf16x8 val = (bf16x8){0,0,0,0,0,0,0,0};
        if (tg < NTAGS) {
            const float* wp = W + tg * KD + p * EMB + j * 8;
            f32x4 lo = *(const f32x4*)wp;
            f32x4 hi = *(const f32x4*)(wp + 4);
            val[0]=(short)f2bf(lo[0]); val[1]=(short)f2bf(lo[1]);
            val[2]=(short)f2bf(lo[2]); val[3]=(short)f2bf(lo[3]);
            val[4]=(short)f2bf(hi[0]); val[5]=(short)f2bf(hi[1]);
            val[6]=(short)f2bf(hi[2]); val[7]=(short)f2bf(hi[3]);
        }
        *(bf16x8*)(wlds + n * 256 + ((j ^ (n & 7)) << 4)) = val;
    }

    // ---- E: this wave's 32 vocab rows (2 n-tiles), fp32 -> bf16 in regs ----
    bf16x8 E[2][4];
    #pragma unroll
    for (int nv = 0; nv < 2; ++nv) {
        int row = vb + wave * 32 + nv * 16 + c;
        bool ok = row < VOCAB;
        const float* rp = emb + (size_t)(ok ? row : 0) * EMB;
        #pragma unroll
        for (int kk = 0; kk < 4; ++kk) {
            f32x4 lo = {0,0,0,0}, hi = {0,0,0,0};
            if (ok) {
                lo = *(const f32x4*)(rp + kk * 32 + q * 8);
                hi = *(const f32x4*)(rp + kk * 32 + q * 8 + 4);
            }
            bf16x8 a;
            a[0]=(short)f2bf(lo[0]); a[1]=(short)f2bf(lo[1]);
            a[2]=(short)f2bf(lo[2]); a[3]=(short)f2bf(lo[3]);
            a[4]=(short)f2bf(hi[0]); a[5]=(short)f2bf(hi[1]);
            a[6]=(short)f2bf(hi[2]); a[7]=(short)f2bf(hi[3]);
            E[nv][kk] = a;
        }
    }
    __syncthreads();

    #pragma unroll
    for (int ng = 0; ng < 5; ++ng) {        // ng == position p
        bf16x8 Wf[4][4];
        #pragma unroll
        for (int mtag = 0; mtag < 4; ++mtag) {
            #pragma unroll
            for (int kk = 0; kk < 4; ++kk) {
                int r  = ng * 64 + mtag * 16 + c;         // Wt row
                int ph = (kk * 4 + q) ^ (c & 7);          // phys chunk (r&7 == c&7)
                Wf[mtag][kk] = *(const bf16x8*)(wlds + r * 256 + ph * 16);
            }
        }
        f32x4 acc[4][2];
        #pragma unroll
        for (int mtag = 0; mtag < 4; ++mtag)
            #pragma unroll
            for (int nv = 0; nv < 2; ++nv)
                acc[mtag][nv] = (f32x4){0.f,0.f,0.f,0.f};
        #pragma unroll
        for (int kk = 0; kk < 4; ++kk)
            #pragma unroll
            for (int mtag = 0; mtag < 4; ++mtag)
                #pragma unroll
                for (int nv = 0; nv < 2; ++nv)
                    acc[mtag][nv] = __builtin_amdgcn_mfma_f32_16x16x32_bf16(
                        Wf[mtag][kk], E[nv][kk], acc[mtag][nv], 0, 0, 0);
        // D[tag=(q*4+j)][v=c]: lane owns vocab row (.. + nv*16 + c),
        // tags mtag*16 + q*4 + j  -> one ushort4 (8B) store per (mtag,nv).
        #pragma unroll
        for (int nv = 0; nv < 2; ++nv) {
            const size_t row = (size_t)(vb + wave * 32 + nv * 16 + c);
            #pragma unroll
            for (int mtag = 0; mtag < 4; ++mtag) {
                ushort4 o = { f2bf(acc[mtag][nv][0]), f2bf(acc[mtag][nv][1]),
                              f2bf(acc[mtag][nv][2]), f2bf(acc[mtag][nv][3]) };
                *(ushort4*)(ZT + row * NZ + ng * 64 + mtag * 16 + q * 4) = o;
            }
        }
    }
}

// per 24-token block: ids->LDS prefetch, batched reg reads, then fully
// independent coalesced gload_lds staging of 28 ZT rows; window-sum,
// softmax, LDS-transpose, NON-TEMPORAL full-line output stores (keep the
// write stream out of L3 so ZT stays L3-resident).
__global__ __launch_bounds__(64, 1)
void tag_k(const int* __restrict__ tokens, const ushort* __restrict__ ZT,
           const float* __restrict__ bias, float* __restrict__ out) {
    __shared__ __align__(16) char smem[RWS * 640 + 128];   // rows + ids
    int* ids = (int*)(smem + RWS * 640);

    const int l  = threadIdx.x;
    const int bb = blockIdx.x * TOK;

    // ---- token ids for the 28 rows (row r <-> token bb-2+r) ----
    {
        int t = bb - 2 + l;
        if (l < RWS) ids[l] = ((unsigned)t < NTOK) ? tokens[t] : VOCAB; // zero row
    }
    __syncthreads();

    // ---- batched id reads into regs (mostly-broadcast LDS reads) ----
    int tk[NITER];
    #pragma unroll
    for (int w = 0; w < NITER; ++w) {
        int g = w * 64 + l;
        int r = (g < NCHUNK) ? (g / CHR) : 0;
        tk[w] = ids[r];
    }

    // ---- coalesced stage: flat chunk g = r*40 + p*8 + i  ->  LDS byte g*16.
    //      all DMA issues independent (ids already in regs); source chunk
    //      pre-swizzled (i ^ (r&7)) so LDS dest stays linear. ----
    #pragma unroll
    for (int w = 0; w < NITER; ++w) {
        int g = w * 64 + l;
        if (g < NCHUNK) {
            int r  = g / CHR;
            int ch = g - r * CHR;
            int i  = ch & 7, p = ch >> 3;
            const char* src = (const char*)ZT + (size_t)tk[w] * 640
                              + p * 128 + ((i ^ (r & 7)) << 4);
            gload_lds16(src, smem + w * 1024);
        }
    }
    __syncthreads();

    // ---- accumulate bias + 5 window slices: slice p of token bb+l lives in
    //      LDS row l+p (token bb+l+p-2). ----
    float acc[56];
    #pragma unroll
    for (int g = 0; g < 12; ++g) {
        float4 b4 = *(const float4*)(bias + g * 4);
        acc[g*4+0] = b4.x; acc[g*4+1] = b4.y; acc[g*4+2] = b4.z; acc[g*4+3] = b4.w;
    }
    acc[48] = bias[48]; acc[49] = bias[49];
    #pragma unroll
    for (int j = 50; j < 56; ++j) acc[j] = 0.f;

    {
        const int le = (l < TOK) ? l : (TOK - 1);   // lanes 24..63: dummy rows
        bf16x8 v[5][7];
        #pragma unroll
        for (int p = 0; p < 5; ++p) {
            const int rp = le + p;                  // LDS row for this slice
            const char* rb = smem + rp * 640;
            const int rx = (rp & 7) << 4;
            #pragma unroll
            for (int j = 0; j < 7; ++j)
                v[p][j] = *(const bf16x8*)(rb + p * 128 + ((j << 4) ^ rx));
        }
        #pragma unroll
        for (int p = 0; p < 5; ++p)
            #pragma unroll
            for (int j = 0; j < 7; ++j)
                #pragma unroll
                for (int e = 0; e < 8; ++e) {
                    unsigned u = (unsigned)(ushort)v[p][j][e] << 16;
                    acc[j*8+e] += __uint_as_float(u);
                }
    }

    // ---- log-softmax over tags 0..49 (all local to the lane) ----
    float m = acc[0];
    #pragma unroll
    for (int j = 1; j < NTAGS; ++j) m = fmaxf(m, acc[j]);
    float s = 0.f;
    #pragma unroll
    for (int j = 0; j < NTAGS; ++j) s += __expf(acc[j] - m);
    const float L = m + __logf(s);

    // ---- LDS transpose -> non-temporal full-line coalesced stores ----
    __syncthreads();
    if (l < TOK) {
        #pragma unroll
        for (int k = 0; k < 25; ++k) {
            float2 st = { acc[2*k] - L, acc[2*k+1] - L };
            *(float2*)(smem + (size_t)l * 200 + k * 8) = st;
        }
    }
    __syncthreads();
    const int nvalid = (NTOK - bb < TOK) ? (NTOK - bb) : TOK;
    const int nbytes = nvalid * 200;
    char* ob = (char*)out + (size_t)bb * 200;
    #pragma unroll
    for (int w = 0; w < 5; ++w) {
        int off = w * 1024 + l * 16;
        if (off < nbytes) {
            f32x4 d = *(const f32x4*)(smem + off);
            __builtin_nontemporal_store(d, (f32x4*)(ob + off));
        }
    }
}

// ============================ fallback path (R4, needs only ~13 MB ws) ============================
__global__ void fb_conv_k(const float* __restrict__ emb, const float* __restrict__ W,
                          ushort* __restrict__ embb, ushort* __restrict__ wb) {
    const int etotal = (VOCAB + 1) * EMB;
    int idx = (blockIdx.x * blockDim.x + threadIdx.x) * 4;
    if (idx < etotal) {
        float4 v = {0.f, 0.f, 0.f, 0.f};
        if (idx < VOCAB * EMB) v = *(const float4*)(emb + idx);
        ushort4 o = { f2bf(v.x), f2bf(v.y), f2bf(v.z), f2bf(v.w) };
        *(ushort4*)(embb + idx) = o;
    } else {
        int wi = idx - etotal;
        if (wi < WPAD * KD) {
            #pragma unroll
            for (int k = 0; k < 4; ++k) {
                int j = wi + k;
                int tag = j / KD;
                wb[j] = f2bf(tag < NTAGS ? W[j] : 0.f);
            }
        }
    }
}

__global__ __launch_bounds__(64, 2)
void fb_tag_k(const int* __restrict__ tokens, const ushort* __restrict__ embb,
              const ushort* __restrict__ Wb, const float* __restrict__ bias,
              float* __restrict__ out) {
    __shared__ ushort smem[68 * EMB];
    const int lane = threadIdx.x & 63;
    const int c = lane & 15;
    const int q = lane >> 4;
    const int bb = blockIdx.x * 64;
    const int rsub = lane >> 4;

    int tokid[17];
    #pragma unroll
    for (int g = 0; g < 17; ++g) {
        int t = bb - 2 + g * 4 + rsub;
        tokid[g] = (t >= 0 && t < NTOK) ? tokens[t] : VOCAB;
    }
    const ushort* bp[4];
    #pragma unroll
    for (int nt = 0; nt < 4; ++nt)
        bp[nt] = Wb + (nt * 16 + c) * KD + q * 8;
    bf16x8 Bb[4][4];
    #pragma unroll
    for (int s = 0; s < 4; ++s)
        #pragma unroll
        for (int nt = 0; nt < 4; ++nt)
            Bb[s][nt] = *(const bf16x8*)(bp[nt] + (s >> 2) * 128 + (s & 3) * 32);
    float bv[4];
    #pragma unroll
    for (int nt = 0; nt < 4; ++nt) {
        int tag = nt * 16 + c;
        bv[nt] = bias[tag < NTAGS ? tag : NTAGS - 1];
    }
    {
        const int pc = lane & 15;
        #pragma unroll
        for (int g = 0; g < 17; ++g) {
            int i = g * 4 + rsub;
            int sc = pc ^ (i & 7);
            gload_lds16(embb + (size_t)tokid[g] * EMB + sc * 8, (char*)smem + g * 1024);
        }
    }
    __syncthreads();

    f32x4 acc[4][4];
    #pragma unroll
    for (int mt = 0; mt < 4; ++mt)
        #pragma unroll
        for (int nt = 0; nt < 4; ++nt)
            acc[mt][nt] = (f32x4){0.f, 0.f, 0.f, 0.f};
    bf16x8 Ab[2][4];
    #pragma unroll
    for (int s = 0; s < 2; ++s) {
        int p = s >> 2, kk = s & 3;
        int ch = (4 * kk + q) ^ ((c + p) & 7);
        const char* ab = (const char*)smem + (c + p) * 256 + ch * 16;
        #pragma unroll
        for (int mt = 0; mt < 4; ++mt)
            Ab[s][mt] = *(const bf16x8*)(ab + mt * 4096);
    }
    #pragma unroll
    for (int s = 0; s < 20; ++s) {
        __builtin_amdgcn_s_setprio(1);
        #pragma unroll
        for (int mt = 0; mt < 4; ++mt)
            #pragma unroll
            for (int nt = 0; nt < 4; ++nt)
                acc[mt][nt] = __builtin_amdgcn_mfma_f32_16x16x32_bf16(
                    Ab[s & 1][mt], Bb[s & 3][nt], acc[mt][nt], 0, 0, 0);
        __builtin_amdgcn_s_setprio(0);
        if (s + 4 < 20) {
            const int tt = s + 4, p = tt >> 2, kk = tt & 3;
            #pragma unroll
            for (int nt = 0; nt < 4; ++nt)
                Bb[s & 3][nt] = *(const bf16x8*)(bp[nt] + p * 128 + kk * 32);
        }
        if (s + 2 < 20) {
            const int tt = s + 2, p = tt >> 2, kk = tt & 3;
            int ch = (4 * kk + q) ^ ((c + p) & 7);
            const char* ab = (const char*)smem + (c + p) * 256 + ch * 16;
            #pragma unroll
            for (int mt = 0; mt < 4; ++mt)
                Ab[s & 1][mt] = *(const bf16x8*)(ab + mt * 4096);
        }
    }
    #pragma unroll
    for (int mt = 0; mt < 4; ++mt) {
        #pragma unroll
        for (int j = 0; j < 4; ++j) {
            const int row = bb + mt * 16 + q * 4 + j;
            float x[4];
            float m = -1e30f;
            #pragma unroll
            for (int nt = 0; nt < 4; ++nt) {
                float xv = acc[mt][nt][j] + bv[nt];
                x[nt] = xv;
                if (nt * 16 + c < NTAGS) m = fmaxf(m, xv);
            }
            #pragma unroll
            for (int mask = 8; mask >= 1; mask >>= 1)
                m = fmaxf(m, __shfl_xor(m, mask));
            float s = 0.f;
            #pragma unroll
            for (int nt = 0; nt < 4; ++nt)
                if (nt * 16 + c < NTAGS) s += __expf(x[nt] - m);
            #pragma unroll
            for (int mask = 8; mask >= 1; mask >>= 1)
                s += __shfl_xor(s, mask);
            const float L = m + __logf(s);
            #pragma unroll
            for (int nt = 0; nt < 4; ++nt) {
                int tag = nt * 16 + c;
                if (tag < NTAGS) out[row * NTAGS + tag] = x[nt] - L;
            }
        }
    }
}

extern "C" void kernel_launch(void* const* d_in, const int* in_sizes, int n_in,
                              void* d_out, int out_size, void* d_ws, size_t ws_size,
                              hipStream_t stream) {
    const int*   tokens = (const int*)d_in[0];
    const float* emb    = (const float*)d_in[1];
    const float* W      = (const float*)d_in[2];
    const float* b      = (const float*)d_in[3];
    float* out = (float*)d_out;

    const size_t NEED = (size_t)ZROWS * NZ * 2ull;   // ~32.2 MB
    if (ws_size >= NEED) {
        ushort* ZT = (ushort*)d_ws;                  // ZROWS x 320 bf16
        zt_k<<<ZROWS / 128, 256, 0, stream>>>(emb, W, ZT);
        tag_k<<<(NTOK + TOK - 1) / TOK, 64, 0, stream>>>(tokens, ZT, b, out);
    } else {
        ushort* embb = (ushort*)d_ws;
        ushort* Wb   = embb + (size_t)(VOCAB + 1) * EMB;
        const int etotal = (VOCAB + 1) * EMB;
        const int total4 = (etotal + WPAD * KD) / 4;
        fb_conv_k<<<(total4 + 255) / 256, 256, 0, stream>>>(emb, W, embb, Wb);
        fb_tag_k<<<NTOK / 64, 64, 0, stream>>>(tokens, embb, Wb, b, out);
    }
}